// Round 5
// baseline (361.574 us; speedup 1.0000x reference)
//
#include <hip/hip_runtime.h>

#define L 21
#define C0 32
#define C1 32
#define IN_DIM 7
#define GHIST 256
#define BPAD 256   // bucket padding -> every 256-slot chunk is layer-uniform
#define NBPL 96    // persistent blocks per layer (21*96 = 2016 blocks, ~all resident)

// ---------------- K1: per-block histogram of idx ----------------
__global__ __launch_bounds__(256) void k_hist(const int* __restrict__ idx, int E,
                                              int* __restrict__ blockCounts) {
  __shared__ int h[L];
  int tid = threadIdx.x;
  if (tid < L) h[tid] = 0;
  __syncthreads();
  int per = (E + GHIST - 1) / GHIST;
  int s = blockIdx.x * per;
  int e = min(E, s + per);
  for (int i = s + tid; i < e; i += blockDim.x)
    atomicAdd(&h[idx[i]], 1);
  __syncthreads();
  if (tid < L) blockCounts[blockIdx.x * L + tid] = h[tid];
}

// ---------------- K2: totals, 256-padded bases, per-block cursors -------------
__global__ __launch_bounds__(256) void k_scan(const int* __restrict__ blockCounts,
                                              int* __restrict__ cursor,
                                              int* __restrict__ endArr,
                                              int* __restrict__ baseArr) {
  __shared__ int tot[L];
  __shared__ int base[L + 1];
  int tid = threadIdx.x;
  if (tid < L) {
    int s = 0;
#pragma unroll 8
    for (int b = 0; b < GHIST; b++) s += blockCounts[b * L + tid];
    tot[tid] = s;
  }
  __syncthreads();
  if (tid == 0) {
    int a = 0;
    for (int l = 0; l < L; l++) { base[l] = a; a += (tot[l] + BPAD - 1) & ~(BPAD - 1); }
    base[L] = a;
  }
  __syncthreads();
  if (tid < L) {
    int a = base[tid];
#pragma unroll 8
    for (int b = 0; b < GHIST; b++) {
      cursor[b * L + tid] = a;
      a += blockCounts[b * L + tid];
    }
    endArr[tid] = base[tid] + tot[tid];
  }
  if (tid <= L) baseArr[tid] = base[tid];
}

// ---------------- K3: scatter edge ids + gather input rows (fused) ------------
__global__ __launch_bounds__(256) void k_scatter(const int* __restrict__ idx,
                                                 const float* __restrict__ inp, int E,
                                                 const int* __restrict__ cursor,
                                                 int* __restrict__ perm,
                                                 float* __restrict__ xb) {
  __shared__ int cur[L];
  int tid = threadIdx.x;
  if (tid < L) cur[tid] = cursor[blockIdx.x * L + tid];
  __syncthreads();
  int per = (E + GHIST - 1) / GHIST;
  int s = blockIdx.x * per;
  int e = min(E, s + per);
  for (int i = s + tid; i < e; i += blockDim.x) {
    int l = idx[i];
    int pos = atomicAdd(&cur[l], 1);
    perm[pos] = i;
    const float* row = inp + (size_t)i * IN_DIM;
    float4 a, b;
    a.x = row[0]; a.y = row[1]; a.z = row[2]; a.w = row[3];
    b.x = row[4]; b.y = row[5]; b.z = row[6]; b.w = 0.f;
    float4* dst = (float4*)(xb + (size_t)pos * 8);
    dst[0] = a;
    dst[1] = b;
  }
}

// ---------------- K4: persistent, layer-pinned compute blocks -----------------
// Block b owns layer b/NBPL; loops chunks b%NBPL, +NBPL, ... of that bucket.
// Scalar weight cache stays warm after the first chunk; weights stream via SGPRs.
template <bool USE_XB>
__global__ __launch_bounds__(256) void k_compute(const float* __restrict__ xb,
                                                 const float* __restrict__ inp,
                                                 const float* __restrict__ W0g,
                                                 const float* __restrict__ b0g,
                                                 const float* __restrict__ W1g,
                                                 const float* __restrict__ b1g,
                                                 const int* __restrict__ perm,
                                                 const int* __restrict__ baseArr,
                                                 const int* __restrict__ endArr,
                                                 float* __restrict__ out) {
  int T = threadIdx.x;
  int lane = T & 63;
  int b = blockIdx.x;
  int l = b / NBPL;
  int j = b - l * NBPL;

  int base0 = baseArr[l];
  int bend  = baseArr[l + 1];
  int end   = endArr[l];

  const float* w0 = W0g + l * (IN_DIM * C0);
  const float* B0 = b0g + l * C0;
  const float* w1 = W1g + l * (C0 * C1);
  const float* B1 = b1g + l * C1;

  __shared__ float obuf[64 * 32];
  int wv = T >> 6;
  int row = T >> 2;      // reader role: row 0..63
  int q = (T & 3) * 8;   // reader column start

  for (int cbase = base0 + j * 256; cbase < bend; cbase += NBPL * 256) {
    int slot = cbase + T;

    // ---- load input row (padding slots read garbage; never stored) ----
    float x[IN_DIM];
    if (USE_XB) {
      const float4* xrow = (const float4*)(xb + (size_t)slot * 8);
      float4 xa = xrow[0], xc = xrow[1];
      x[0] = xa.x; x[1] = xa.y; x[2] = xa.z; x[3] = xa.w;
      x[4] = xc.x; x[5] = xc.y; x[6] = xc.z;
    } else {
      int p0 = slot < end ? perm[slot] : 0;
      const float* rowp = inp + (size_t)p0 * IN_DIM;
#pragma unroll
      for (int k = 0; k < IN_DIM; k++) x[k] = rowp[k];
    }

    float h[C0];
#pragma unroll
    for (int c = 0; c < C0; c++) h[c] = B0[c];
#pragma unroll
    for (int k = 0; k < IN_DIM; k++) {
#pragma unroll
      for (int c = 0; c < C0; c++) h[c] = fmaf(x[k], w0[k * C0 + c], h[c]);
    }
#pragma unroll
    for (int c = 0; c < C0; c++) h[c] = h[c] >= 0.f ? h[c] : 0.2f * h[c];

    float o[C1];
#pragma unroll
    for (int c = 0; c < C1; c++) o[c] = B1[c];
#pragma unroll
    for (int k = 0; k < C0; k++) {
#pragma unroll
      for (int c = 0; c < C1; c++) o[c] = fmaf(h[k], w1[k * C1 + c], o[c]);
    }
#pragma unroll
    for (int c = 0; c < C1; c++) o[c] = o[c] >= 0.f ? o[c] : 0.2f * o[c];

    // ---- chunked LDS transpose epilogue: 64 rows (8KB) at a time ----
#pragma unroll
    for (int c = 0; c < 4; c++) {
      if (wv == c) {
#pragma unroll
        for (int cq = 0; cq < 32; cq += 4) {
          int ad = lane * 32 + (cq ^ ((lane & 7) << 2));
          float4 v = {o[cq], o[cq + 1], o[cq + 2], o[cq + 3]};
          *(float4*)&obuf[ad] = v;
        }
      }
      __syncthreads();
      int slot_r = cbase + c * 64 + row;
      if (slot_r < end) {
        int p = perm[slot_r];
        int sw = (row & 7) << 2;
        float4 v0 = *(const float4*)&obuf[row * 32 + (q ^ sw)];
        float4 v1 = *(const float4*)&obuf[row * 32 + ((q + 4) ^ sw)];
        float* dst = out + (size_t)p * C1 + q;
        *(float4*)dst = v0;
        *(float4*)(dst + 4) = v1;
      }
      __syncthreads();
    }
  }
}

extern "C" void kernel_launch(void* const* d_in, const int* in_sizes, int n_in,
                              void* d_out, int out_size, void* d_ws, size_t ws_size,
                              hipStream_t stream) {
  const float* inp = (const float*)d_in[0];
  const int* idx   = (const int*)d_in[1];
  const float* W0  = (const float*)d_in[2];
  const float* b0  = (const float*)d_in[3];
  const float* W1  = (const float*)d_in[4];
  const float* b1  = (const float*)d_in[5];
  float* out = (float*)d_out;
  int E = in_sizes[1];

  int nBlk = (E + 255) / 256 + L;  // upper bound on padded 256-chunks
  size_t slots = (size_t)nBlk * 256;

  int* ws = (int*)d_ws;
  int* blockCounts = ws;                       // GHIST*L
  int* cursor      = blockCounts + GHIST * L;  // GHIST*L
  int* endArr      = cursor + GHIST * L;       // L
  int* baseArr     = endArr + L;               // L+1
  int* perm        = baseArr + (L + 1);        // slots
  size_t ints = (size_t)2 * GHIST * L + L + (L + 1) + slots;
  ints = (ints + 3) & ~(size_t)3;              // 16B-align xb
  float* xb = (float*)(ws + ints);             // slots * 8 floats
  size_t need = ints * 4 + slots * 8 * 4;
  bool use_xb = ws_size >= need;

  k_hist<<<GHIST, 256, 0, stream>>>(idx, E, blockCounts);
  k_scan<<<1, 256, 0, stream>>>(blockCounts, cursor, endArr, baseArr);
  k_scatter<<<GHIST, 256, 0, stream>>>(idx, inp, E, cursor, perm, xb);

  if (use_xb) {
    k_compute<true><<<L * NBPL, 256, 0, stream>>>(xb, inp, W0, b0, W1, b1,
                                                  perm, baseArr, endArr, out);
  } else {
    k_compute<false><<<L * NBPL, 256, 0, stream>>>(nullptr, inp, W0, b0, W1, b1,
                                                   perm, baseArr, endArr, out);
  }
}

// Round 6
// 87.420 us; speedup vs baseline: 4.1361x; 4.1361x over previous
//
#include <hip/hip_runtime.h>

#define L 21
#define C0 32
#define C1 32
#define IN_DIM 7
#define GHIST 256
#define BPAD 256  // bucket padding -> every 256-slot chunk is layer-uniform

// ---------------- K1: per-block histogram of idx ----------------
__global__ __launch_bounds__(256) void k_hist(const int* __restrict__ idx, int E,
                                              int* __restrict__ blockCounts) {
  __shared__ int h[L];
  int tid = threadIdx.x;
  if (tid < L) h[tid] = 0;
  __syncthreads();
  int per = (E + GHIST - 1) / GHIST;
  int s = blockIdx.x * per;
  int e = min(E, s + per);
  for (int i = s + tid; i < e; i += blockDim.x)
    atomicAdd(&h[idx[i]], 1);
  __syncthreads();
  if (tid < L) blockCounts[blockIdx.x * L + tid] = h[tid];
}

// ---------------- K2: totals, 256-padded bases, per-block cursors -------------
__global__ __launch_bounds__(256) void k_scan(const int* __restrict__ blockCounts,
                                              int* __restrict__ cursor,
                                              int* __restrict__ endArr,
                                              int* __restrict__ baseArr) {
  __shared__ int tot[L];
  __shared__ int base[L + 1];
  int tid = threadIdx.x;
  if (tid < L) {
    int s = 0;
#pragma unroll 8
    for (int b = 0; b < GHIST; b++) s += blockCounts[b * L + tid];
    tot[tid] = s;
  }
  __syncthreads();
  if (tid == 0) {
    int a = 0;
    for (int l = 0; l < L; l++) { base[l] = a; a += (tot[l] + BPAD - 1) & ~(BPAD - 1); }
    base[L] = a;
  }
  __syncthreads();
  if (tid < L) {
    int a = base[tid];
#pragma unroll 8
    for (int b = 0; b < GHIST; b++) {
      cursor[b * L + tid] = a;
      a += blockCounts[b * L + tid];
    }
    endArr[tid] = base[tid] + tot[tid];
  }
  if (tid <= L) baseArr[tid] = base[tid];
}

// ---------------- K3: scatter edge ids + gather input rows (fused) ------------
__global__ __launch_bounds__(256) void k_scatter(const int* __restrict__ idx,
                                                 const float* __restrict__ inp, int E,
                                                 const int* __restrict__ cursor,
                                                 int* __restrict__ perm,
                                                 float* __restrict__ xb) {
  __shared__ int cur[L];
  int tid = threadIdx.x;
  if (tid < L) cur[tid] = cursor[blockIdx.x * L + tid];
  __syncthreads();
  int per = (E + GHIST - 1) / GHIST;
  int s = blockIdx.x * per;
  int e = min(E, s + per);
  for (int i = s + tid; i < e; i += blockDim.x) {
    int l = idx[i];
    int pos = atomicAdd(&cur[l], 1);
    perm[pos] = i;
    const float* row = inp + (size_t)i * IN_DIM;
    float4 a, b;
    a.x = row[0]; a.y = row[1]; a.z = row[2]; a.w = row[3];
    b.x = row[4]; b.y = row[5]; b.z = row[6]; b.w = 0.f;
    float4* dst = (float4*)(xb + (size_t)pos * 8);
    dst[0] = a;
    dst[1] = b;
  }
}

// ---------------- K4: compute. Block-uniform l; BARRIER-FREE per-wave epilogue
// Each wave owns a private 8KB XOR-swizzled 64x32 tile: ds_write own rows,
// lgkmcnt-only wait, ds_read columns, coalesced 128B-row global stores.
template <bool USE_XB>
__global__ __launch_bounds__(256) void k_compute(const float* __restrict__ xb,
                                                 const float* __restrict__ inp,
                                                 const float* __restrict__ W0g,
                                                 const float* __restrict__ b0g,
                                                 const float* __restrict__ W1g,
                                                 const float* __restrict__ b1g,
                                                 const int* __restrict__ perm,
                                                 const int* __restrict__ baseArr,
                                                 const int* __restrict__ endArr,
                                                 float* __restrict__ out) {
  int T = threadIdx.x;
  int lane = T & 63;
  int blockbase = blockIdx.x << 8;

  // derive this block's layer from baseArr (blocks never straddle buckets)
  int bv = baseArr[lane <= L ? lane : L];
  unsigned long long m = __ballot((lane <= L) && (blockbase >= bv));
  int l = __popcll(m) - 1;
  if (l >= L) return;  // past all data (uniform across block)
  l = __builtin_amdgcn_readfirstlane(l);
  int end = __builtin_amdgcn_readfirstlane(endArr[l]);

  int slot = blockbase + T;

  // ---- load input row (padding slots read garbage; never stored) ----
  float x[IN_DIM];
  if (USE_XB) {
    const float4* xrow = (const float4*)(xb + (size_t)slot * 8);
    float4 xa = xrow[0], xc = xrow[1];
    x[0] = xa.x; x[1] = xa.y; x[2] = xa.z; x[3] = xa.w;
    x[4] = xc.x; x[5] = xc.y; x[6] = xc.z;
  } else {
    int p0 = slot < end ? perm[slot] : 0;
    const float* row = inp + (size_t)p0 * IN_DIM;
#pragma unroll
    for (int k = 0; k < IN_DIM; k++) x[k] = row[k];
  }

  const float* w0 = W0g + l * (IN_DIM * C0);
  const float* B0 = b0g + l * C0;
  const float* w1 = W1g + l * (C0 * C1);
  const float* B1 = b1g + l * C1;

  float h[C0];
#pragma unroll
  for (int c = 0; c < C0; c++) h[c] = B0[c];
#pragma unroll
  for (int k = 0; k < IN_DIM; k++) {
#pragma unroll
    for (int c = 0; c < C0; c++) h[c] = fmaf(x[k], w0[k * C0 + c], h[c]);
  }
#pragma unroll
  for (int c = 0; c < C0; c++) h[c] = h[c] >= 0.f ? h[c] : 0.2f * h[c];

  float o[C1];
#pragma unroll
  for (int c = 0; c < C1; c++) o[c] = B1[c];
#pragma unroll
  for (int k = 0; k < C0; k++) {
#pragma unroll
    for (int c = 0; c < C1; c++) o[c] = fmaf(h[k], w1[k * C1 + c], o[c]);
  }
#pragma unroll
  for (int c = 0; c < C1; c++) o[c] = o[c] >= 0.f ? o[c] : 0.2f * o[c];

  // ---- per-wave transpose tile (no cross-wave sharing -> no barriers) ----
  __shared__ float obuf[4 * 64 * 32];
  float* tile = &obuf[(T >> 6) * (64 * 32)];
  // write own row, XOR-swizzled (keeps 16B alignment; 2-way banks = free)
#pragma unroll
  for (int cq = 0; cq < 32; cq += 4) {
    int ad = lane * 32 + (cq ^ ((lane & 7) << 2));
    float4 v = {o[cq], o[cq + 1], o[cq + 2], o[cq + 3]};
    *(float4*)&tile[ad] = v;
  }
  // read columns: 8 lanes per row -> 128B contiguous global bursts per row
  int wavebase = blockbase + (T >> 6) * 64;
  int q = (lane & 7) * 4;
  int rbase = lane >> 3;
#pragma unroll
  for (int step = 0; step < 8; step++) {
    int row = step * 8 + rbase;
    int slot_r = wavebase + row;
    if (slot_r < end) {
      int p = perm[slot_r];  // 8-lane broadcast, coalescer merges
      int sw = (row & 7) << 2;
      float4 v = *(const float4*)&tile[row * 32 + (q ^ sw)];
      *(float4*)(out + (size_t)p * C1 + q) = v;
    }
  }
}

extern "C" void kernel_launch(void* const* d_in, const int* in_sizes, int n_in,
                              void* d_out, int out_size, void* d_ws, size_t ws_size,
                              hipStream_t stream) {
  const float* inp = (const float*)d_in[0];
  const int* idx   = (const int*)d_in[1];
  const float* W0  = (const float*)d_in[2];
  const float* b0  = (const float*)d_in[3];
  const float* W1  = (const float*)d_in[4];
  const float* b1  = (const float*)d_in[5];
  float* out = (float*)d_out;
  int E = in_sizes[1];

  int nBlk = (E + 255) / 256 + L;  // upper bound on padded 256-chunks
  size_t slots = (size_t)nBlk * 256;

  int* ws = (int*)d_ws;
  int* blockCounts = ws;                       // GHIST*L
  int* cursor      = blockCounts + GHIST * L;  // GHIST*L
  int* endArr      = cursor + GHIST * L;       // L
  int* baseArr     = endArr + L;               // L+1
  int* perm        = baseArr + (L + 1);        // slots
  size_t ints = (size_t)2 * GHIST * L + L + (L + 1) + slots;
  ints = (ints + 3) & ~(size_t)3;              // 16B-align xb
  float* xb = (float*)(ws + ints);             // slots * 8 floats
  size_t need = ints * 4 + slots * 8 * 4;
  bool use_xb = ws_size >= need;

  k_hist<<<GHIST, 256, 0, stream>>>(idx, E, blockCounts);
  k_scan<<<1, 256, 0, stream>>>(blockCounts, cursor, endArr, baseArr);
  k_scatter<<<GHIST, 256, 0, stream>>>(idx, inp, E, cursor, perm, xb);

  if (use_xb) {
    k_compute<true><<<nBlk, 256, 0, stream>>>(xb, inp, W0, b0, W1, b1,
                                              perm, baseArr, endArr, out);
  } else {
    k_compute<false><<<nBlk, 256, 0, stream>>>(nullptr, inp, W0, b0, W1, b1,
                                               perm, baseArr, endArr, out);
  }
}